// Round 2
// baseline (1121.842 us; speedup 1.0000x reference)
//
#include <hip/hip_runtime.h>
#include <hip/hip_bf16.h>

// GATv2 x3 layers for MI355X. All float tensors are FLOAT32 (per reference);
// edge_index is int32. Output float32.

#define NN 10000    // nodes
#define NE 200000   // edges
#define ND 128      // node dim (layer 0 input)
#define ED 16       // edge dim
#define CD 64       // conv dim (per head)
#define NH 5        // heads
#define HC 320      // NH*CD
#define EF 210000   // NE + NN (with self loops)
#define NEG 0.2f

// ---- degree + sum of incoming edge_attr (for self-loop 'mean' fill) ----
__global__ void k_deg(const int* __restrict__ dst, const float* __restrict__ eattr,
                      float* __restrict__ deg, float* __restrict__ loop_sum) {
  int e = blockIdx.x * blockDim.x + threadIdx.x;
  if (e >= NE) return;
  int d = dst[e];
  atomicAdd(&deg[d], 1.0f);
  #pragma unroll
  for (int k = 0; k < ED; k++)
    atomicAdd(&loop_sum[d * ED + k], eattr[e * ED + k]);
}

__global__ void k_loopnorm(float* __restrict__ loop_attr, const float* __restrict__ deg) {
  int i = blockIdx.x * blockDim.x + threadIdx.x;
  if (i >= NN * ED) return;
  loop_attr[i] /= fmaxf(deg[i / ED], 1.0f);
}

// ---- xl = h @ Wl + bl  (tile: 16 nodes x 320 cols per block, 320 threads) ----
template <int D>
__global__ __launch_bounds__(320) void k_xl(const float* __restrict__ h,
                                            const float* __restrict__ Wl,
                                            const float* __restrict__ bl,
                                            float* __restrict__ xl) {
  __shared__ float xs[16 * D];
  int node0 = blockIdx.x * 16;
  int t = threadIdx.x;  // 0..319 -> output column
  for (int i = t; i < 16 * D; i += 320)
    xs[i] = h[(node0 + i / D) * D + (i % D)];
  __syncthreads();
  float acc[16];
  #pragma unroll
  for (int i = 0; i < 16; i++) acc[i] = 0.f;
  for (int k = 0; k < D; k++) {
    float w = Wl[k * HC + t];
    #pragma unroll
    for (int i = 0; i < 16; i++) acc[i] += xs[i * D + k] * w;
  }
  float bias = bl[t];
  #pragma unroll
  for (int i = 0; i < 16; i++)
    xl[(node0 + i) * HC + t] = acc[i] + bias;
}

// ---- scores: wave per edge; e_emb computed on the fly; atomicMax seg-max ----
__global__ __launch_bounds__(256) void k_score(
    const int* __restrict__ ei, const float* __restrict__ eattr,
    const float* __restrict__ loop_attr, const float* __restrict__ xl,
    const float* __restrict__ We, const float* __restrict__ att,
    float* __restrict__ score, unsigned int* __restrict__ smax) {
  __shared__ float Ws[ED * HC];  // 20 KB
  int t = threadIdx.x;
  for (int i = t; i < ED * HC; i += 256) Ws[i] = We[i];
  __syncthreads();
  int lane = t & 63, wave = t >> 6;
  float attv[NH];
  #pragma unroll
  for (int h = 0; h < NH; h++) attv[h] = att[h * CD + lane];
  int stride = gridDim.x * 4;
  for (int e = blockIdx.x * 4 + wave; e < EF; e += stride) {
    int s, d;
    float ea[ED];
    if (e < NE) {
      s = ei[e]; d = ei[NE + e];
      #pragma unroll
      for (int k = 0; k < ED; k++) ea[k] = eattr[e * ED + k];
    } else {
      s = d = e - NE;
      #pragma unroll
      for (int k = 0; k < ED; k++) ea[k] = loop_attr[s * ED + k];
    }
    float sc[NH];
    #pragma unroll
    for (int h = 0; h < NH; h++) {
      int c = h * CD + lane;
      float v = xl[s * HC + c] + xl[d * HC + c];
      #pragma unroll
      for (int k = 0; k < ED; k++) v += ea[k] * Ws[k * HC + c];
      v = v > 0.f ? v : NEG * v;
      sc[h] = v * attv[h];
    }
    #pragma unroll
    for (int off = 32; off; off >>= 1) {
      #pragma unroll
      for (int h = 0; h < NH; h++) sc[h] += __shfl_xor(sc[h], off, 64);
    }
    if (lane == 0) {
      #pragma unroll
      for (int h = 0; h < NH; h++) {
        score[e * NH + h] = sc[h];
        unsigned int b = __float_as_uint(sc[h]);
        unsigned int key = b ^ ((unsigned int)((int)b >> 31) | 0x80000000u);
        atomicMax(&smax[d * NH + h], key);
      }
    }
  }
}

// ---- ex = exp(score - max); denom accumulate ----
__global__ void k_exp(const int* __restrict__ ei, float* __restrict__ score,
                      const unsigned int* __restrict__ smax, float* __restrict__ denom) {
  int e = blockIdx.x * blockDim.x + threadIdx.x;
  if (e >= EF) return;
  int d = (e < NE) ? ei[NE + e] : e - NE;
  #pragma unroll
  for (int h = 0; h < NH; h++) {
    unsigned int key = smax[d * NH + h];
    unsigned int b = (key & 0x80000000u) ? (key ^ 0x80000000u) : ~key;
    float ex = expf(score[e * NH + h] - __uint_as_float(b));
    score[e * NH + h] = ex;
    atomicAdd(&denom[d * NH + h], ex);
  }
}

// ---- aggregate: out_acc[dst,c] += (1/NH) * sum_h alpha_h * xl[src,h,c] ----
__global__ __launch_bounds__(256) void k_agg(const int* __restrict__ ei,
                                             const float* __restrict__ ex,
                                             const float* __restrict__ denom,
                                             const float* __restrict__ xl,
                                             float* __restrict__ out_acc) {
  int t = threadIdx.x;
  int lane = t & 63, wave = t >> 6;
  int stride = gridDim.x * 4;
  for (int e = blockIdx.x * 4 + wave; e < EF; e += stride) {
    int s, d;
    if (e < NE) { s = ei[e]; d = ei[NE + e]; }
    else        { s = d = e - NE; }
    float val = 0.f;
    #pragma unroll
    for (int h = 0; h < NH; h++) {
      float alpha = ex[e * NH + h] / denom[d * NH + h];
      val += alpha * xl[s * HC + h * CD + lane];
    }
    atomicAdd(&out_acc[d * CD + lane], val * (1.0f / NH));
  }
}

// ---- finalize: + bias, elu ----
__global__ void k_final(const float* __restrict__ out_acc, const float* __restrict__ bias,
                        float* __restrict__ hnext) {
  int i = blockIdx.x * blockDim.x + threadIdx.x;
  if (i >= NN * CD) return;
  float v = out_acc[i] + bias[i & (CD - 1)];
  v = v > 0.f ? v : expm1f(v);
  hnext[i] = v;
}

extern "C" void kernel_launch(void* const* d_in, const int* in_sizes, int n_in,
                              void* d_out, int out_size, void* d_ws, size_t ws_size,
                              hipStream_t stream) {
  const float* x = (const float*)d_in[0];
  const int* ei = (const int*)d_in[1];      // [2, NE]: src row then dst row
  const float* eattr = (const float*)d_in[2];

  float* ws = (float*)d_ws;
  float* deg       = ws;                        // NN
  float* loop_attr = deg + NN;                  // NN*ED
  float* xl        = loop_attr + NN * ED;       // NN*HC
  float* score     = xl + NN * HC;              // EF*NH
  unsigned int* smax = (unsigned int*)(score + EF * NH);  // NN*NH
  float* denom     = (float*)smax + NN * NH;    // NN*NH
  float* out_acc   = denom + NN * NH;           // NN*CD
  float* hbuf      = out_acc + NN * CD;         // NN*CD

  // degree + loop_attr (layer-invariant)
  hipMemsetAsync(deg, 0, (size_t)(NN + NN * ED) * sizeof(float), stream);
  k_deg<<<(NE + 255) / 256, 256, 0, stream>>>(ei + NE, eattr, deg, loop_attr);
  k_loopnorm<<<(NN * ED + 255) / 256, 256, 0, stream>>>(loop_attr, deg);

  for (int l = 0; l < 3; l++) {
    const float* Wl  = (const float*)d_in[3 + 5 * l];
    const float* bl  = (const float*)d_in[4 + 5 * l];
    const float* We  = (const float*)d_in[5 + 5 * l];
    const float* att = (const float*)d_in[6 + 5 * l];
    const float* b   = (const float*)d_in[7 + 5 * l];

    if (l == 0) k_xl<ND><<<NN / 16, 320, 0, stream>>>(x, Wl, bl, xl);
    else        k_xl<CD><<<NN / 16, 320, 0, stream>>>(hbuf, Wl, bl, xl);

    hipMemsetAsync(smax, 0, (size_t)NN * NH * sizeof(unsigned int), stream);
    hipMemsetAsync(denom, 0, (size_t)NN * NH * sizeof(float), stream);
    hipMemsetAsync(out_acc, 0, (size_t)NN * CD * sizeof(float), stream);

    k_score<<<2048, 256, 0, stream>>>(ei, eattr, loop_attr, xl, We, att, score, smax);
    k_exp<<<(EF + 255) / 256, 256, 0, stream>>>(ei, score, smax, denom);
    k_agg<<<2048, 256, 0, stream>>>(ei, score, denom, xl, out_acc);

    if (l < 2) k_final<<<(NN * CD + 255) / 256, 256, 0, stream>>>(out_acc, b, hbuf);
    else       k_final<<<(NN * CD + 255) / 256, 256, 0, stream>>>(out_acc, b, (float*)d_out);
  }
}

// Round 3
// 740.130 us; speedup vs baseline: 1.5157x; 1.5157x over previous
//
#include <hip/hip_runtime.h>
#include <hip/hip_bf16.h>

// GATv2 x3 layers for MI355X. f32 in/out; edge_index int32.
// Round 3: CSR-by-dst built per call; all softmax/agg done as per-dst gathers
// (no scattered float atomics — those were memory-side RMW at ~600 GB/s).

#define NN 10000    // nodes
#define NE 200000   // edges
#define ND 128      // node dim (layer 0 input)
#define ED 16       // edge dim
#define CD 64       // conv dim (per head)
#define NH 5        // heads
#define HC 320      // NH*CD
#define EF 210000   // NE + NN (with self loops)
#define NEG 0.2f

// ---- CSR build: count ----
__global__ void k_count(const int* __restrict__ dst, int* __restrict__ deg) {
  int e = blockIdx.x * blockDim.x + threadIdx.x;
  if (e >= NE) return;
  atomicAdd(&deg[dst[e]], 1);
}

// ---- CSR build: exclusive scan (single block, 256 threads x 40 elems) ----
__global__ __launch_bounds__(256) void k_scan(const int* __restrict__ deg,
                                              int* __restrict__ rowptr) {
  __shared__ int part[256];
  int t = threadIdx.x;
  int base = t * 40;
  int local[40];
  int s = 0;
  #pragma unroll
  for (int j = 0; j < 40; j++) {
    int i = base + j;
    local[j] = (i < NN) ? deg[i] : 0;
    s += local[j];
  }
  part[t] = s;
  __syncthreads();
  for (int off = 1; off < 256; off <<= 1) {
    int v = (t >= off) ? part[t - off] : 0;
    __syncthreads();
    part[t] += v;
    __syncthreads();
  }
  int prefix = (t > 0) ? part[t - 1] : 0;
  #pragma unroll
  for (int j = 0; j < 40; j++) {
    int i = base + j;
    if (i < NN) rowptr[i] = prefix;
    prefix += local[j];
  }
  if (t == 255) rowptr[NN] = prefix;
}

// ---- CSR build: fill slots ----
__global__ void k_fill(const int* __restrict__ ei, const int* __restrict__ rowptr,
                       int* __restrict__ cursor, int* __restrict__ csr_eid,
                       int* __restrict__ csr_src) {
  int e = blockIdx.x * blockDim.x + threadIdx.x;
  if (e >= NE) return;
  int d = ei[NE + e];
  int slot = atomicAdd(&cursor[d], 1);
  int pos = rowptr[d] + slot;
  csr_eid[pos] = e;
  csr_src[pos] = ei[e];
}

// ---- loop_attr = mean of incoming edge_attr (gather, wave per node) ----
__global__ __launch_bounds__(256) void k_loopattr(const int* __restrict__ csr_eid,
                                                  const int* __restrict__ rowptr,
                                                  const float* __restrict__ eattr,
                                                  float* __restrict__ loop_attr) {
  int wave = threadIdx.x >> 6, lane = threadIdx.x & 63;
  int d = blockIdx.x * 4 + wave;
  if (d >= NN) return;
  int g = lane >> 4, k = lane & 15;
  int b = rowptr[d], n = rowptr[d + 1] - b;
  float s = 0.f;
  for (int i = g; i < n; i += 4)
    s += eattr[csr_eid[b + i] * ED + k];
  s += __shfl_xor(s, 16, 64);
  s += __shfl_xor(s, 32, 64);
  if (g == 0) loop_attr[d * ED + k] = s / fmaxf((float)n, 1.0f);
}

// ---- xl = h @ Wl + bl  (tile: 16 nodes x 320 cols per block, 320 threads) ----
template <int D>
__global__ __launch_bounds__(320) void k_xl(const float* __restrict__ h,
                                            const float* __restrict__ Wl,
                                            const float* __restrict__ bl,
                                            float* __restrict__ xl) {
  __shared__ float xs[16 * D];
  int node0 = blockIdx.x * 16;
  int t = threadIdx.x;
  for (int i = t; i < 16 * D; i += 320)
    xs[i] = h[(node0 + i / D) * D + (i % D)];
  __syncthreads();
  float acc[16];
  #pragma unroll
  for (int i = 0; i < 16; i++) acc[i] = 0.f;
  for (int k = 0; k < D; k++) {
    float w = Wl[k * HC + t];
    #pragma unroll
    for (int i = 0; i < 16; i++) acc[i] += xs[i * D + k] * w;
  }
  float bias = bl[t];
  #pragma unroll
  for (int i = 0; i < 16; i++)
    xl[(node0 + i) * HC + t] = acc[i] + bias;
}

// ---- scores: wave per edge; e_emb on the fly; writes score only ----
__global__ __launch_bounds__(256) void k_score(
    const int* __restrict__ ei, const float* __restrict__ eattr,
    const float* __restrict__ loop_attr, const float* __restrict__ xl,
    const float* __restrict__ We, const float* __restrict__ att,
    float* __restrict__ score) {
  __shared__ float Ws[ED * HC];  // 20 KB
  int t = threadIdx.x;
  for (int i = t; i < ED * HC; i += 256) Ws[i] = We[i];
  __syncthreads();
  int lane = t & 63, wave = t >> 6;
  float attv[NH];
  #pragma unroll
  for (int h = 0; h < NH; h++) attv[h] = att[h * CD + lane];
  int stride = gridDim.x * 4;
  for (int e = blockIdx.x * 4 + wave; e < EF; e += stride) {
    int s, d;
    float ea[ED];
    if (e < NE) {
      s = ei[e]; d = ei[NE + e];
      #pragma unroll
      for (int k = 0; k < ED; k++) ea[k] = eattr[e * ED + k];
    } else {
      s = d = e - NE;
      #pragma unroll
      for (int k = 0; k < ED; k++) ea[k] = loop_attr[s * ED + k];
    }
    float sc[NH];
    #pragma unroll
    for (int h = 0; h < NH; h++) {
      int c = h * CD + lane;
      float v = xl[s * HC + c] + xl[d * HC + c];
      #pragma unroll
      for (int k = 0; k < ED; k++) v += ea[k] * Ws[k * HC + c];
      v = v > 0.f ? v : NEG * v;
      sc[h] = v * attv[h];
    }
    #pragma unroll
    for (int off = 32; off; off >>= 1) {
      #pragma unroll
      for (int h = 0; h < NH; h++) sc[h] += __shfl_xor(sc[h], off, 64);
    }
    if (lane == 0) {
      #pragma unroll
      for (int h = 0; h < NH; h++) score[e * NH + h] = sc[h];
    }
  }
}

// ---- per-dst softmax + aggregate + bias + head-mean + elu (wave per node) ----
__global__ __launch_bounds__(256) void k_gat(const int* __restrict__ csr_eid,
                                             const int* __restrict__ csr_src,
                                             const int* __restrict__ rowptr,
                                             const float* __restrict__ score,
                                             const float* __restrict__ xl,
                                             const float* __restrict__ bias,
                                             float* __restrict__ out) {
  int wave = threadIdx.x >> 6, lane = threadIdx.x & 63;
  int d = blockIdx.x * 4 + wave;
  if (d >= NN) return;
  int b = rowptr[d], nreal = rowptr[d + 1] - b;
  int tot = nreal + 1;  // + self loop
  // phase 1: per-head max over incoming edges
  float m[NH];
  #pragma unroll
  for (int h = 0; h < NH; h++) m[h] = -1e30f;
  for (int i = lane; i < tot; i += 64) {
    int eid = (i < nreal) ? csr_eid[b + i] : (NE + d);
    #pragma unroll
    for (int h = 0; h < NH; h++) m[h] = fmaxf(m[h], score[eid * NH + h]);
  }
  #pragma unroll
  for (int off = 32; off; off >>= 1) {
    #pragma unroll
    for (int h = 0; h < NH; h++) m[h] = fmaxf(m[h], __shfl_xor(m[h], off, 64));
  }
  // phase 2: denom
  float dn[NH];
  #pragma unroll
  for (int h = 0; h < NH; h++) dn[h] = 0.f;
  for (int i = lane; i < tot; i += 64) {
    int eid = (i < nreal) ? csr_eid[b + i] : (NE + d);
    #pragma unroll
    for (int h = 0; h < NH; h++) dn[h] += __expf(score[eid * NH + h] - m[h]);
  }
  #pragma unroll
  for (int off = 32; off; off >>= 1) {
    #pragma unroll
    for (int h = 0; h < NH; h++) dn[h] += __shfl_xor(dn[h], off, 64);
  }
  float rdn[NH];
  #pragma unroll
  for (int h = 0; h < NH; h++) rdn[h] = 1.0f / dn[h];
  // phase 3: accumulate (edges serial, lane = output channel)
  float acc = 0.f;
  for (int i = 0; i < tot; i++) {
    int eid, s;
    if (i < nreal) { eid = csr_eid[b + i]; s = csr_src[b + i]; }
    else           { eid = NE + d;         s = d; }
    #pragma unroll
    for (int h = 0; h < NH; h++) {
      float alpha = __expf(score[eid * NH + h] - m[h]) * rdn[h];
      acc += alpha * xl[s * HC + h * CD + lane];
    }
  }
  float v = acc * (1.0f / NH) + bias[lane];
  v = v > 0.f ? v : expm1f(v);
  out[d * CD + lane] = v;
}

extern "C" void kernel_launch(void* const* d_in, const int* in_sizes, int n_in,
                              void* d_out, int out_size, void* d_ws, size_t ws_size,
                              hipStream_t stream) {
  const float* x = (const float*)d_in[0];
  const int* ei = (const int*)d_in[1];      // [2, NE]: src row then dst row
  const float* eattr = (const float*)d_in[2];

  char* w = (char*)d_ws;
  int* degi      = (int*)w;                       w += NN * 4;
  int* cursor    = (int*)w;                       w += NN * 4;
  int* rowptr    = (int*)w;                       w += (NN + 1) * 4;
  int* csr_eid   = (int*)w;                       w += NE * 4;
  int* csr_src   = (int*)w;                       w += NE * 4;
  float* loop_attr = (float*)w;                   w += NN * ED * 4;
  float* xl      = (float*)w;                     w += NN * HC * 4;
  float* score   = (float*)w;                     w += (size_t)EF * NH * 4;
  float* hbuf    = (float*)w;                     w += NN * CD * 4;

  hipMemsetAsync(degi, 0, NN * 4, stream);
  hipMemsetAsync(cursor, 0, NN * 4, stream);
  k_count<<<(NE + 255) / 256, 256, 0, stream>>>(ei + NE, degi);
  k_scan<<<1, 256, 0, stream>>>(degi, rowptr);
  k_fill<<<(NE + 255) / 256, 256, 0, stream>>>(ei, rowptr, cursor, csr_eid, csr_src);
  k_loopattr<<<(NN + 3) / 4, 256, 0, stream>>>(csr_eid, rowptr, eattr, loop_attr);

  for (int l = 0; l < 3; l++) {
    const float* Wl  = (const float*)d_in[3 + 5 * l];
    const float* bl  = (const float*)d_in[4 + 5 * l];
    const float* We  = (const float*)d_in[5 + 5 * l];
    const float* att = (const float*)d_in[6 + 5 * l];
    const float* b   = (const float*)d_in[7 + 5 * l];

    if (l == 0) k_xl<ND><<<NN / 16, 320, 0, stream>>>(x, Wl, bl, xl);
    else        k_xl<CD><<<NN / 16, 320, 0, stream>>>(hbuf, Wl, bl, xl);

    k_score<<<2048, 256, 0, stream>>>(ei, eattr, loop_attr, xl, We, att, score);

    float* dst_out = (l < 2) ? hbuf : (float*)d_out;
    k_gat<<<(NN + 3) / 4, 256, 0, stream>>>(csr_eid, csr_src, rowptr, score, xl, b, dst_out);
  }
}